// Round 25
// baseline (156.884 us; speedup 1.0000x reference)
//
#include <hip/hip_runtime.h>
#include <hip/hip_bf16.h>

#define B_TOT 2048
#define N_CAP 200
#define D_DIM 256
#define NT    512
#define NW    8               // waves per block
#define CPW   25              // capsules per wave (200/8, exact)

__device__ __forceinline__ float bf_lo(unsigned u) { return __uint_as_float(u << 16); }
__device__ __forceinline__ float bf_hi(unsigned u) { return __uint_as_float(u & 0xffff0000u); }

// ---- DPP wave reduction (R22 win: 157 -> 104us) ----------------------------
// row_shr 1/2/4/8 + row_bcast15/31, zero-fill: 6 pure-VALU ops, no LDS pipe
// (vs __shfl_xor = 6 dependent ds_bpermute LDS round-trips — the hidden
// serializer through R20). Full sum lands in LANE 63.
template <int CTRL, int RMASK>
__device__ __forceinline__ float dpp_term(float v) {
    return __int_as_float(__builtin_amdgcn_update_dpp(
        0, __float_as_int(v), CTRL, RMASK, 0xf, true));
}
__device__ __forceinline__ float wave_red63(float v) {
    v += dpp_term<0x111, 0xf>(v);   // row_shr:1
    v += dpp_term<0x112, 0xf>(v);   // row_shr:2
    v += dpp_term<0x114, 0xf>(v);   // row_shr:4
    v += dpp_term<0x118, 0xf>(v);   // row_shr:8  -> lane 15 of each row = row sum
    v += dpp_term<0x142, 0xa>(v);   // row_bcast15 -> rows 1,3 accumulate
    v += dpp_term<0x143, 0xc>(v);   // row_bcast31 -> lane 63 = full sum
    return v;
}
__device__ __forceinline__ float bcast63(float v) {
    return __int_as_float(__builtin_amdgcn_readlane(__float_as_int(v), 63));
}

// Anchor = R24 (104us: R17 structure + DPP + LB(512,4) [",4" load-bearing,
// R23] + merged softmax barrier). R25 delta: OWNER-MAPPED wave-autonomous
// iteration. Lane i of wave w owns capsule n = w+8i end-to-end: exp reads
// b_lds[n] written by its own wave's lane 63 (R8-proven same-wave pattern),
// w_lds[n] is written+read only by wave w (no barrier), and the einsum moves
// BEFORE B1 (needs only own w_lds + regs; cs applied post-einsum). Per iter:
// exp -> w_lds -> red -> EINSUM -> B1(red) -> cs/s_part -> B2 -> squash ->
// agreement. 2 barriers/iter, B3 deleted; einsum hides in B1's wait window.
// out_c: scattered 25-lane write, last iter only (800B/block).
// Probes that LOST (do not retry): fused agreement+einsum accums (R3/R4
// spill), LB(...,8) (R9), LB(256,4)+u[50] (R18), argless LB (R23 +41us),
// per-capsule sched_barrier (R6), LDS-split u (R7), lane-select psel gather
// (R11 wrong c), inline e*inv in einsum (R12), 1024-thr blocks (R13),
// persistent+DMA (R14), two-pass norm (R15), load/norm split (R16),
// lgkm-only barriers + DMA (R19).
__global__ __launch_bounds__(NT, 4)
void dyr_kernel(const float* __restrict__ embeds,
                const float* __restrict__ weights,
                float* __restrict__ out_v,
                float* __restrict__ out_c)
{
    __shared__ float s_part[NW][D_DIM];   // 8 KB
    __shared__ float red[NW];
    __shared__ float b_lds[N_CAP];        // routing logits; wave w owns slots w+8i
    __shared__ float w_lds[N_CAP];        // unscaled weights e_n*inv_n (wave-local)
    __shared__ float inv_lds[N_CAP];      // 1 / max(||x_n||, 1e-12)

    const int b    = blockIdx.x;
    const int t    = threadIdx.x;
    const int wave = t >> 6;
    const int lane = t & 63;

    // ---- init logits (coalesced; owner waves read after B0) ----
    if (t < N_CAP) b_lds[t] = weights[(size_t)b * N_CAP + t];

    // ---- Load embeds ONCE; RAW x -> bf16 regs; 1/||x|| -> LDS.
    // wave w, lane l holds capsule n = w + 8i, dims [4l, 4l+4).
    // 5 chunks x 5 in-flight float4 loads (proven schedule). ----
    const float* eb = embeds + (size_t)b * (N_CAP * D_DIM) + lane * 4;

    uint2 u[CPW];   // 50 VGPRs, raw x packed bf16
#pragma unroll
    for (int cc = 0; cc < 5; ++cc) {
        float4 xs[5];
#pragma unroll
        for (int j = 0; j < 5; ++j) {
            const int n = wave + (cc * 5 + j) * NW;
            xs[j] = *reinterpret_cast<const float4*>(eb + n * D_DIM);
        }
#pragma unroll
        for (int j = 0; j < 5; ++j) {
            const float4 x = xs[j];
            float ss = fmaf(x.x, x.x, fmaf(x.y, x.y, fmaf(x.z, x.z, x.w * x.w)));
            ss = wave_red63(ss);
            if (lane == 63)
                inv_lds[wave + (cc * 5 + j) * NW] = 1.0f / fmaxf(sqrtf(ss), 1e-12f);
            union { __hip_bfloat16 h[4]; uint2 q; } pk;
            pk.h[0] = __float2bfloat16(x.x);
            pk.h[1] = __float2bfloat16(x.y);
            pk.h[2] = __float2bfloat16(x.z);
            pk.h[3] = __float2bfloat16(x.w);
            u[cc * 5 + j] = pk.q;
        }
    }
    __syncthreads();   // B0: b_lds/inv_lds visible

    // ---- 3 routing iterations: 2 barriers each ----
    for (int r = 0; r < 3; ++r) {
        // owner-mapped softmax numerator + unscaled weight (all wave-local:
        // b_lds/inv_lds/w_lds slots w+8i touched only by wave w after B0)
        float e = 0.f;
        if (lane < CPW) {
            const int n = wave + NW * lane;
            e = __expf(b_lds[n]);            // same-wave RAW (lane63 wrote it)
            w_lds[n] = e * inv_lds[n];       // unscaled; cs applied post-einsum
        }
        const float ep = wave_red63(e);
        if (lane == 63) red[wave] = ep;

        // einsum BEFORE B1 (hides in the barrier's wait window): reads only
        // own-wave w_lds slots + registers.
        float4 acc = make_float4(0.f, 0.f, 0.f, 0.f);
#pragma unroll
        for (int i = 0; i < CPW; ++i) {
            const float wn = w_lds[wave + NW * i];   // wave-uniform broadcast
            acc.x = fmaf(wn, bf_lo(u[i].x), acc.x);
            acc.y = fmaf(wn, bf_hi(u[i].x), acc.y);
            acc.z = fmaf(wn, bf_lo(u[i].y), acc.z);
            acc.w = fmaf(wn, bf_hi(u[i].y), acc.w);
        }
        __syncthreads();                          // B1: red[] visible

        float es = 0.f;
#pragma unroll
        for (int w = 0; w < NW; ++w) es += red[w];
        const float cs = (float)N_CAP / es;
        if (r == 2 && lane < CPW)                 // c = e*cs, scattered (once)
            out_c[(size_t)b * N_CAP + wave + NW * lane] = e * cs;

        acc.x *= cs; acc.y *= cs; acc.z *= cs; acc.w *= cs;
        *reinterpret_cast<float4*>(&s_part[wave][lane * 4]) = acc;
        __syncthreads();                          // B2: s_part visible

        // WAVE-REDUNDANT squash: this wave's 64 lanes span all 256 dims,
        // so the wave reduction of |sd|^2 is the full ssn (readlane bcast).
        float4 sd = make_float4(0.f, 0.f, 0.f, 0.f);
#pragma unroll
        for (int w = 0; w < NW; ++w) {
            const float4 p = *reinterpret_cast<const float4*>(&s_part[w][lane * 4]);
            sd.x += p.x; sd.y += p.y; sd.z += p.z; sd.w += p.w;
        }
        float ssn = fmaf(sd.x, sd.x, fmaf(sd.y, sd.y, fmaf(sd.z, sd.z, sd.w * sd.w)));
        ssn = bcast63(wave_red63(ssn));
        const float scale = ssn / (1.0f + ssn) * rsqrtf(ssn + 1e-9f);
        const float4 vv = make_float4(scale * sd.x, scale * sd.y,
                                      scale * sd.z, scale * sd.w);

        if (r == 2) {
            if (wave == 0)
                *reinterpret_cast<float4*>(&out_v[(size_t)b * D_DIM + lane * 4]) = vv;
        } else {
            // agreement: b_n += (x_n . v) * inv_n (lane-63 owner-slot update);
            // next iteration's exp reads the slot SAME-WAVE -> no barrier.
#pragma unroll
            for (int i = 0; i < CPW; ++i) {
                float p = fmaf(bf_lo(u[i].x), vv.x,
                          fmaf(bf_hi(u[i].x), vv.y,
                          fmaf(bf_lo(u[i].y), vv.z,
                               bf_hi(u[i].y) * vv.w)));
                p = wave_red63(p);
                if (lane == 63) {
                    const int n = wave + NW * i;
                    b_lds[n] = fmaf(p, inv_lds[n], b_lds[n]);
                }
            }
        }
    }
}

extern "C" void kernel_launch(void* const* d_in, const int* in_sizes, int n_in,
                              void* d_out, int out_size, void* d_ws, size_t ws_size,
                              hipStream_t stream) {
    const float* embeds  = (const float*)d_in[0];
    const float* weights = (const float*)d_in[1];
    float* out   = (float*)d_out;
    float* out_v = out;                                  // [2048, 256]
    float* out_c = out + (size_t)B_TOT * D_DIM;          // [2048, 200]

    dyr_kernel<<<B_TOT, NT, 0, stream>>>(embeds, weights, out_v, out_c);
}

// Round 26
// 146.834 us; speedup vs baseline: 1.0684x; 1.0684x over previous
//
#include <hip/hip_runtime.h>
#include <hip/hip_bf16.h>

#define B_TOT 2048
#define N_CAP 200
#define D_DIM 256
#define NT    512
#define NW    8               // waves per block
#define CPW   25              // capsules per wave (200/8, exact)

__device__ __forceinline__ float bf_lo(unsigned u) { return __uint_as_float(u << 16); }
__device__ __forceinline__ float bf_hi(unsigned u) { return __uint_as_float(u & 0xffff0000u); }

// ---- DPP wave reduction (R22 win: 157 -> 104us) ----------------------------
// row_shr 1/2/4/8 + row_bcast15/31, zero-fill: 6 pure-VALU ops, no LDS pipe
// (vs __shfl_xor = 6 dependent ds_bpermute LDS round-trips — the hidden
// serializer through R20). Full sum lands in LANE 63.
template <int CTRL, int RMASK>
__device__ __forceinline__ float dpp_term(float v) {
    return __int_as_float(__builtin_amdgcn_update_dpp(
        0, __float_as_int(v), CTRL, RMASK, 0xf, true));
}
__device__ __forceinline__ float wave_red63(float v) {
    v += dpp_term<0x111, 0xf>(v);   // row_shr:1
    v += dpp_term<0x112, 0xf>(v);   // row_shr:2
    v += dpp_term<0x114, 0xf>(v);   // row_shr:4
    v += dpp_term<0x118, 0xf>(v);   // row_shr:8  -> lane 15 of each row = row sum
    v += dpp_term<0x142, 0xa>(v);   // row_bcast15 -> rows 1,3 accumulate
    v += dpp_term<0x143, 0xc>(v);   // row_bcast31 -> lane 63 = full sum
    return v;
}
__device__ __forceinline__ float bcast63(float v) {
    return __int_as_float(__builtin_amdgcn_readlane(__float_as_int(v), 63));
}

// Anchor = R24 (103.7us best: R17 structure + DPP reductions + LB(512,4)
// [",4" load-bearing, R23] + merged softmax barrier). R26 sole delta:
// s_setprio(1) around the per-iteration routing compute. The 2 co-resident
// blocks/CU are INDEPENDENT (one loads while the other routes) — the m191
// regime where setprio pays: routing waves win VALU arbitration, loader
// waves keep VMEM issue. Runtime-only hint; zero regalloc impact.
// Probes that LOST (do not retry): fused agreement+einsum accums (R3/R4
// spill), LB(...,8) (R9), LB(256,4)+u[50] (R18), argless LB (R23 +41us),
// owner-mapped wave-autonomous iteration (R25 +53us), per-capsule
// sched_barrier (R6), LDS-split u (R7), lane-select psel gather (R11),
// inline e*inv in einsum (R12), 1024-thr blocks (R13), persistent+DMA (R14),
// two-pass norm (R15), load/norm split (R16), lgkm-only barriers+DMA (R19).
__global__ __launch_bounds__(NT, 4)
void dyr_kernel(const float* __restrict__ embeds,
                const float* __restrict__ weights,
                float* __restrict__ out_v,
                float* __restrict__ out_c)
{
    __shared__ float s_part[NW][D_DIM];   // 8 KB
    __shared__ float red[NW];
    __shared__ float b_lds[N_CAP];        // routing logits
    __shared__ float w_lds[N_CAP];        // unscaled einsum weights e_n * inv_n
    __shared__ float inv_lds[N_CAP];      // 1 / max(||x_n||, 1e-12)

    const int b    = blockIdx.x;
    const int t    = threadIdx.x;
    const int wave = t >> 6;
    const int lane = t & 63;

    // ---- init logits ----
    if (t < N_CAP) b_lds[t] = weights[(size_t)b * N_CAP + t];

    // ---- Load embeds ONCE; RAW x -> bf16 regs; 1/||x|| -> LDS.
    // wave w, lane l holds capsule n = w + 8i, dims [4l, 4l+4).
    // 5 chunks x 5 in-flight float4 loads (proven schedule). ----
    const float* eb = embeds + (size_t)b * (N_CAP * D_DIM) + lane * 4;

    uint2 u[CPW];   // 50 VGPRs, raw x packed bf16
#pragma unroll
    for (int cc = 0; cc < 5; ++cc) {
        float4 xs[5];
#pragma unroll
        for (int j = 0; j < 5; ++j) {
            const int n = wave + (cc * 5 + j) * NW;
            xs[j] = *reinterpret_cast<const float4*>(eb + n * D_DIM);
        }
#pragma unroll
        for (int j = 0; j < 5; ++j) {
            const float4 x = xs[j];
            float ss = fmaf(x.x, x.x, fmaf(x.y, x.y, fmaf(x.z, x.z, x.w * x.w)));
            ss = wave_red63(ss);
            if (lane == 63)
                inv_lds[wave + (cc * 5 + j) * NW] = 1.0f / fmaxf(sqrtf(ss), 1e-12f);
            union { __hip_bfloat16 h[4]; uint2 q; } pk;
            pk.h[0] = __float2bfloat16(x.x);
            pk.h[1] = __float2bfloat16(x.y);
            pk.h[2] = __float2bfloat16(x.z);
            pk.h[3] = __float2bfloat16(x.w);
            u[cc * 5 + j] = pk.q;
        }
    }
    __syncthreads();   // inv_lds/b_lds visible

    // ---- 3 routing iterations: 3 barriers each (2 on the last) ----
    for (int r = 0; r < 3; ++r) {
        // softmax numerator + UNSCALED weight, staged before ONE barrier.
        // (no max-subtraction: |b| <= ~8, fp32 exp safe)
        float e = 0.f;
        if (t < N_CAP) {
            e = __expf(b_lds[t]);
            w_lds[t] = e * inv_lds[t];           // unscaled; cs applied post-einsum
        }
        const float ep = wave_red63(e);
        if (lane == 63) red[wave] = ep;
        __syncthreads();                          // B1: red[] AND w_lds visible

        __builtin_amdgcn_s_setprio(1);            // routing compute: prefer this
        float es = 0.f;                           // wave on the VALU while the
#pragma unroll                                    // co-resident block loads
        for (int w = 0; w < NW; ++w) es += red[w];
        const float cs = (float)N_CAP / es;
        if (r == 2 && t < N_CAP)                  // c = e * N/es (e in register)
            out_c[(size_t)b * N_CAP + t] = e * cs;

        // einsum partial: acc = cs * sum_i w_i * x_i (hot loop unchanged)
        float4 acc = make_float4(0.f, 0.f, 0.f, 0.f);
#pragma unroll
        for (int i = 0; i < CPW; ++i) {
            const float wn = w_lds[wave + NW * i];   // wave-uniform broadcast
            acc.x = fmaf(wn, bf_lo(u[i].x), acc.x);
            acc.y = fmaf(wn, bf_hi(u[i].x), acc.y);
            acc.z = fmaf(wn, bf_lo(u[i].y), acc.z);
            acc.w = fmaf(wn, bf_hi(u[i].y), acc.w);
        }
        acc.x *= cs; acc.y *= cs; acc.z *= cs; acc.w *= cs;
        *reinterpret_cast<float4*>(&s_part[wave][lane * 4]) = acc;
        __builtin_amdgcn_s_setprio(0);
        __syncthreads();                          // B2: s_part visible

        __builtin_amdgcn_s_setprio(1);
        // WAVE-REDUNDANT squash: this wave's 64 lanes span all 256 dims,
        // so the wave reduction of |sd|^2 is the full ssn (readlane bcast).
        float4 sd = make_float4(0.f, 0.f, 0.f, 0.f);
#pragma unroll
        for (int w = 0; w < NW; ++w) {
            const float4 p = *reinterpret_cast<const float4*>(&s_part[w][lane * 4]);
            sd.x += p.x; sd.y += p.y; sd.z += p.z; sd.w += p.w;
        }
        float ssn = fmaf(sd.x, sd.x, fmaf(sd.y, sd.y, fmaf(sd.z, sd.z, sd.w * sd.w)));
        ssn = bcast63(wave_red63(ssn));
        const float scale = ssn / (1.0f + ssn) * rsqrtf(ssn + 1e-9f);
        const float4 vv = make_float4(scale * sd.x, scale * sd.y,
                                      scale * sd.z, scale * sd.w);

        if (r == 2) {
            if (wave == 0)
                *reinterpret_cast<float4*>(&out_v[(size_t)b * D_DIM + lane * 4]) = vv;
        } else {
            // agreement: b_n += (x_n . v) * inv_n  (lane-63 owner-slot update);
            // vv in registers — no LDS read before this.
#pragma unroll
            for (int i = 0; i < CPW; ++i) {
                float p = fmaf(bf_lo(u[i].x), vv.x,
                          fmaf(bf_hi(u[i].x), vv.y,
                          fmaf(bf_lo(u[i].y), vv.z,
                               bf_hi(u[i].y) * vv.w)));
                p = wave_red63(p);
                if (lane == 63) {
                    const int n = wave + NW * i;
                    b_lds[n] = fmaf(p, inv_lds[n], b_lds[n]);
                }
            }
        }
        __builtin_amdgcn_s_setprio(0);
        if (r < 2) __syncthreads();               // B3: b_lds visible for next iter
    }
}

extern "C" void kernel_launch(void* const* d_in, const int* in_sizes, int n_in,
                              void* d_out, int out_size, void* d_ws, size_t ws_size,
                              hipStream_t stream) {
    const float* embeds  = (const float*)d_in[0];
    const float* weights = (const float*)d_in[1];
    float* out   = (float*)d_out;
    float* out_v = out;                                  // [2048, 256]
    float* out_c = out + (size_t)B_TOT * D_DIM;          // [2048, 200]

    dyr_kernel<<<B_TOT, NT, 0, stream>>>(embeds, weights, out_v, out_c);
}

// Round 27
// 103.475 us; speedup vs baseline: 1.5162x; 1.4190x over previous
//
#include <hip/hip_runtime.h>
#include <hip/hip_bf16.h>

#define B_TOT 2048
#define N_CAP 200
#define D_DIM 256
#define NT    512
#define NW    8               // waves per block
#define CPW   25              // capsules per wave (200/8, exact)

__device__ __forceinline__ float bf_lo(unsigned u) { return __uint_as_float(u << 16); }
__device__ __forceinline__ float bf_hi(unsigned u) { return __uint_as_float(u & 0xffff0000u); }

// ---- DPP wave reduction (R22 win: 157 -> 104us) ----------------------------
// row_shr 1/2/4/8 + row_bcast15/31, zero-fill: 6 pure-VALU ops, no LDS pipe
// (vs __shfl_xor = 6 dependent ds_bpermute LDS round-trips — the hidden
// serializer through R20). Full sum lands in LANE 63.
template <int CTRL, int RMASK>
__device__ __forceinline__ float dpp_term(float v) {
    return __int_as_float(__builtin_amdgcn_update_dpp(
        0, __float_as_int(v), CTRL, RMASK, 0xf, true));
}
__device__ __forceinline__ float wave_red63(float v) {
    v += dpp_term<0x111, 0xf>(v);   // row_shr:1
    v += dpp_term<0x112, 0xf>(v);   // row_shr:2
    v += dpp_term<0x114, 0xf>(v);   // row_shr:4
    v += dpp_term<0x118, 0xf>(v);   // row_shr:8  -> lane 15 of each row = row sum
    v += dpp_term<0x142, 0xa>(v);   // row_bcast15 -> rows 1,3 accumulate
    v += dpp_term<0x143, 0xc>(v);   // row_bcast31 -> lane 63 = full sum
    return v;
}
__device__ __forceinline__ float bcast63(float v) {
    return __int_as_float(__builtin_amdgcn_readlane(__float_as_int(v), 63));
}

// FINAL = R24 (103.7us, best of 27 rounds). Structure: one block per batch;
// u_hat as raw bf16 in regs (u[25], 50 VGPRs); 1/||x|| in LDS, norm folded
// into einsum weight; 5x5-deep load chunks; DPP wave reductions (the -34%
// win); wave-redundant squash; merged softmax barrier; LB(512,4) — the ",4"
// is load-bearing (R23: argless = +41us).
// Probes that LOST (do not retry): fused agreement+einsum accums (R3/R4
// spill), LB(...,8) (R9: 32 VGPR), LB(256,4)+u[50] (R18: 845MB spill),
// argless LB (R23 +41us), owner-mapped wave-autonomy (R25 +53us), setprio
// around compute (R26 +43us), per-capsule sched_barrier (R6), LDS-split u
// (R7), lane-select psel gather (R11 wrong c), inline e*inv in einsum (R12),
// 1024-thr blocks (R13), persistent+DMA (R14), two-pass norm (R15),
// load/norm split (R16 neutral), lgkm-only barriers + DMA (R19).
__global__ __launch_bounds__(NT, 4)
void dyr_kernel(const float* __restrict__ embeds,
                const float* __restrict__ weights,
                float* __restrict__ out_v,
                float* __restrict__ out_c)
{
    __shared__ float s_part[NW][D_DIM];   // 8 KB
    __shared__ float red[NW];
    __shared__ float b_lds[N_CAP];        // routing logits
    __shared__ float w_lds[N_CAP];        // unscaled einsum weights e_n * inv_n
    __shared__ float inv_lds[N_CAP];      // 1 / max(||x_n||, 1e-12)

    const int b    = blockIdx.x;
    const int t    = threadIdx.x;
    const int wave = t >> 6;
    const int lane = t & 63;

    // ---- init logits ----
    if (t < N_CAP) b_lds[t] = weights[(size_t)b * N_CAP + t];

    // ---- Load embeds ONCE; RAW x -> bf16 regs; 1/||x|| -> LDS.
    // wave w, lane l holds capsule n = w + 8i, dims [4l, 4l+4).
    // 5 chunks x 5 in-flight float4 loads (proven schedule). ----
    const float* eb = embeds + (size_t)b * (N_CAP * D_DIM) + lane * 4;

    uint2 u[CPW];   // 50 VGPRs, raw x packed bf16
#pragma unroll
    for (int cc = 0; cc < 5; ++cc) {
        float4 xs[5];
#pragma unroll
        for (int j = 0; j < 5; ++j) {
            const int n = wave + (cc * 5 + j) * NW;
            xs[j] = *reinterpret_cast<const float4*>(eb + n * D_DIM);
        }
#pragma unroll
        for (int j = 0; j < 5; ++j) {
            const float4 x = xs[j];
            float ss = fmaf(x.x, x.x, fmaf(x.y, x.y, fmaf(x.z, x.z, x.w * x.w)));
            ss = wave_red63(ss);
            if (lane == 63)
                inv_lds[wave + (cc * 5 + j) * NW] = 1.0f / fmaxf(sqrtf(ss), 1e-12f);
            union { __hip_bfloat16 h[4]; uint2 q; } pk;
            pk.h[0] = __float2bfloat16(x.x);
            pk.h[1] = __float2bfloat16(x.y);
            pk.h[2] = __float2bfloat16(x.z);
            pk.h[3] = __float2bfloat16(x.w);
            u[cc * 5 + j] = pk.q;
        }
    }
    __syncthreads();   // inv_lds/b_lds visible

    // ---- 3 routing iterations: 3 barriers each (2 on the last) ----
    for (int r = 0; r < 3; ++r) {
        // softmax numerator + UNSCALED weight, staged before ONE barrier.
        // (no max-subtraction: |b| <= ~8, fp32 exp safe)
        float e = 0.f;
        if (t < N_CAP) {
            e = __expf(b_lds[t]);
            w_lds[t] = e * inv_lds[t];           // unscaled; cs applied post-einsum
        }
        const float ep = wave_red63(e);
        if (lane == 63) red[wave] = ep;
        __syncthreads();                          // B1: red[] AND w_lds visible

        float es = 0.f;
#pragma unroll
        for (int w = 0; w < NW; ++w) es += red[w];
        const float cs = (float)N_CAP / es;
        if (r == 2 && t < N_CAP)                  // c = e * N/es (e in register)
            out_c[(size_t)b * N_CAP + t] = e * cs;

        // einsum partial: acc = cs * sum_i w_i * x_i (hot loop unchanged)
        float4 acc = make_float4(0.f, 0.f, 0.f, 0.f);
#pragma unroll
        for (int i = 0; i < CPW; ++i) {
            const float wn = w_lds[wave + NW * i];   // wave-uniform broadcast
            acc.x = fmaf(wn, bf_lo(u[i].x), acc.x);
            acc.y = fmaf(wn, bf_hi(u[i].x), acc.y);
            acc.z = fmaf(wn, bf_lo(u[i].y), acc.z);
            acc.w = fmaf(wn, bf_hi(u[i].y), acc.w);
        }
        acc.x *= cs; acc.y *= cs; acc.z *= cs; acc.w *= cs;
        *reinterpret_cast<float4*>(&s_part[wave][lane * 4]) = acc;
        __syncthreads();                          // B2: s_part visible

        // WAVE-REDUNDANT squash: this wave's 64 lanes span all 256 dims,
        // so the wave reduction of |sd|^2 is the full ssn (readlane bcast).
        float4 sd = make_float4(0.f, 0.f, 0.f, 0.f);
#pragma unroll
        for (int w = 0; w < NW; ++w) {
            const float4 p = *reinterpret_cast<const float4*>(&s_part[w][lane * 4]);
            sd.x += p.x; sd.y += p.y; sd.z += p.z; sd.w += p.w;
        }
        float ssn = fmaf(sd.x, sd.x, fmaf(sd.y, sd.y, fmaf(sd.z, sd.z, sd.w * sd.w)));
        ssn = bcast63(wave_red63(ssn));
        const float scale = ssn / (1.0f + ssn) * rsqrtf(ssn + 1e-9f);
        const float4 vv = make_float4(scale * sd.x, scale * sd.y,
                                      scale * sd.z, scale * sd.w);

        if (r == 2) {
            if (wave == 0)
                *reinterpret_cast<float4*>(&out_v[(size_t)b * D_DIM + lane * 4]) = vv;
        } else {
            // agreement: b_n += (x_n . v) * inv_n  (lane-63 owner-slot update);
            // vv in registers — no LDS read before this.
#pragma unroll
            for (int i = 0; i < CPW; ++i) {
                float p = fmaf(bf_lo(u[i].x), vv.x,
                          fmaf(bf_hi(u[i].x), vv.y,
                          fmaf(bf_lo(u[i].y), vv.z,
                               bf_hi(u[i].y) * vv.w)));
                p = wave_red63(p);
                if (lane == 63) {
                    const int n = wave + NW * i;
                    b_lds[n] = fmaf(p, inv_lds[n], b_lds[n]);
                }
            }
            __syncthreads();                      // B3: b_lds visible for next iter
        }
    }
}

extern "C" void kernel_launch(void* const* d_in, const int* in_sizes, int n_in,
                              void* d_out, int out_size, void* d_ws, size_t ws_size,
                              hipStream_t stream) {
    const float* embeds  = (const float*)d_in[0];
    const float* weights = (const float*)d_in[1];
    float* out   = (float*)d_out;
    float* out_v = out;                                  // [2048, 256]
    float* out_c = out + (size_t)B_TOT * D_DIM;          // [2048, 200]

    dyr_kernel<<<B_TOT, NT, 0, stream>>>(embeds, weights, out_v, out_c);
}